// Round 9
// baseline (207.861 us; speedup 1.0000x reference)
//
#include <hip/hip_runtime.h>
#include <math.h>

typedef __attribute__((ext_vector_type(8))) short short8;
typedef __attribute__((ext_vector_type(4))) float floatx4;

typedef __attribute__((address_space(1))) const unsigned int as1_uint;
typedef __attribute__((address_space(3))) unsigned int as3_uint;
#define GLD16(g, l) __builtin_amdgcn_global_load_lds((as1_uint*)(g), (as3_uint*)(l), 16, 0, 0)

__device__ __forceinline__ unsigned short f2bf(float f) {
    unsigned int u = __float_as_uint(f);
    return (unsigned short)((u + 0x7fffu + ((u >> 16) & 1u)) >> 16);
}
__device__ __forceinline__ float bf2f(unsigned short h) {
    return __uint_as_float(((unsigned int)h) << 16);
}

// ---------------------------------------------------------------------------
// convert_all: blocks [0,8192): x rows -> Axhl bf16 [hi|lo] + rs1/rq1 + zero
// accumulators. blocks [8192,10112): weights -> B1..B4 bf16 [hi|lo] + rowsums.
// ---------------------------------------------------------------------------
__global__ __launch_bounds__(256) void convert_all(
    const float* __restrict__ x, unsigned short* __restrict__ Axhl,
    const float* __restrict__ H1, const float* __restrict__ W1,
    const float* __restrict__ H2, const float* __restrict__ W2,
    const float* __restrict__ H3, const float* __restrict__ W3,
    const float* __restrict__ W4,
    unsigned short* __restrict__ B1, unsigned short* __restrict__ B2,
    unsigned short* __restrict__ B3, unsigned short* __restrict__ B4,
    float* __restrict__ rs1, float* __restrict__ rq1,
    float* __restrict__ rs2, float* __restrict__ rq2,
    float* __restrict__ rs3, float* __restrict__ rq3,
    float* __restrict__ rsH1, float* __restrict__ rsH2, float* __restrict__ rsH3,
    float* __restrict__ score1, float* __restrict__ score2,
    float* __restrict__ score3, int* __restrict__ ctr)
{
    const int b = blockIdx.x, tid = threadIdx.x;
    if (b < 8192) {
        if (b == 0) {
            score1[tid] = 0.f; score2[tid] = 0.f; score3[tid] = 0.f;
            if (tid < 8) ctr[tid] = 0;
        }
        if (tid == 0) { rs2[b] = 0.f; rq2[b] = 0.f; rs3[b] = 0.f; rq3[b] = 0.f; }
        float4 v = *(const float4*)(x + (size_t)b * 1024 + (tid << 2));
        ushort4 h, l;
        h.x = f2bf(v.x); l.x = f2bf(v.x - bf2f(h.x));
        h.y = f2bf(v.y); l.y = f2bf(v.y - bf2f(h.y));
        h.z = f2bf(v.z); l.z = f2bf(v.z - bf2f(h.z));
        h.w = f2bf(v.w); l.w = f2bf(v.w - bf2f(h.w));
        *(ushort4*)(Axhl + (size_t)b * 2048 + (tid << 2)) = h;
        *(ushort4*)(Axhl + (size_t)b * 2048 + 1024 + (tid << 2)) = l;
        float s = v.x + v.y + v.z + v.w;
        float qq = v.x*v.x + v.y*v.y + v.z*v.z + v.w*v.w;
#pragma unroll
        for (int d = 1; d < 64; d <<= 1) { s += __shfl_xor(s, d, 64); qq += __shfl_xor(qq, d, 64); }
        __shared__ float sS[4], sQ[4];
        if ((tid & 63) == 0) { sS[tid >> 6] = s; sQ[tid >> 6] = qq; }
        __syncthreads();
        if (tid == 0) {
            rs1[b] = sS[0] + sS[1] + sS[2] + sS[3];
            rq1[b] = sQ[0] + sQ[1] + sQ[2] + sQ[3];
        }
    } else {
        const int wb = b - 8192;
        const float* src; unsigned short* dst; int K; float* rsum = nullptr;
        if (wb < 256)      { K = 1024; src = H1 + (size_t)wb * 1024;         dst = B1 + (size_t)wb * 2048;        rsum = rsH1 + wb; }
        else if (wb < 512) { K = 1024; src = W1 + (size_t)(wb - 256) * 1024; dst = B1 + (size_t)wb * 2048; }
        else if (wb < 640) { K = 256;  src = H2 + (size_t)(wb - 512) * 256;  dst = B2 + (size_t)(wb - 512) * 512; rsum = rsH2 + (wb - 512); }
        else if (wb < 768) { K = 256;  src = W2 + (size_t)(wb - 640) * 256;  dst = B2 + (size_t)(wb - 512) * 512; }
        else if (wb < 832) { K = 128;  src = H3 + (size_t)(wb - 768) * 128;  dst = B3 + (size_t)(wb - 768) * 256; rsum = rsH3 + (wb - 768); }
        else if (wb < 896) { K = 128;  src = W3 + (size_t)(wb - 832) * 128;  dst = B3 + (size_t)(wb - 768) * 256; }
        else { K = 64; int r = wb - 896; src = (r < 1000) ? (W4 + (size_t)r * 64) : nullptr; dst = B4 + (size_t)r * 128; }
        float lsum = 0.f;
        if (tid * 4 < K) {
            float4 v = src ? *(const float4*)(src + tid * 4) : make_float4(0.f, 0.f, 0.f, 0.f);
            ushort4 h, l;
            h.x = f2bf(v.x); l.x = f2bf(v.x - bf2f(h.x));
            h.y = f2bf(v.y); l.y = f2bf(v.y - bf2f(h.y));
            h.z = f2bf(v.z); l.z = f2bf(v.z - bf2f(h.z));
            h.w = f2bf(v.w); l.w = f2bf(v.w - bf2f(h.w));
            *(ushort4*)(dst + tid * 4) = h;
            *(ushort4*)(dst + K + tid * 4) = l;
            lsum = v.x + v.y + v.z + v.w;
        }
        if (rsum) {
#pragma unroll
            for (int d = 1; d < 64; d <<= 1) lsum += __shfl_xor(lsum, d, 64);
            __shared__ float sW[4];
            if ((tid & 63) == 0) sW[tid >> 6] = lsum;
            __syncthreads();
            if (tid == 0) *rsum = sW[0] + sW[1] + sW[2] + sW[3];
        }
    }
}

// ---------------------------------------------------------------------------
// hebb_dev: one block, 64 rows of T (prev layer): wgt=(rs/sqrt(rq))/||T_row||;
// score[y] += T[b,y]*wgt[b]; last arriving block does minmax -> hm.
// smem overlaid on caller's LDS (needs ~6.2 KB).
// ---------------------------------------------------------------------------
__device__ void hebb_dev(char* smem, int hb,
    const float* __restrict__ T, const float* __restrict__ rs,
    const float* __restrict__ rq, const float* __restrict__ rowsumH,
    float* __restrict__ score, int* __restrict__ counter,
    float* __restrict__ hm, int ysize, int nHebb)
{
    float* sPart = (float*)smem;                 // 4*256
    float* sMin  = sPart + 1024;                 // 256
    float* sMax  = sMin + 256;                   // 256
    int*   lastFlag = (int*)(sMax + 256);
    const int tid = threadIdx.x, lane = tid & 63, wave = tid >> 6;
    const int vecsz = ysize >> 6;
    const int b0 = hb * 64;
    float accv[4] = {0.f, 0.f, 0.f, 0.f};
    for (int r = wave; r < 64; r += 4) {
        const float* Trow = T + (size_t)(b0 + r) * ysize;
        float vals[4] = {0.f, 0.f, 0.f, 0.f};
        if (vecsz == 4)      { float4 t = *(const float4*)(Trow + (lane << 2)); vals[0]=t.x; vals[1]=t.y; vals[2]=t.z; vals[3]=t.w; }
        else if (vecsz == 2) { float2 t = *(const float2*)(Trow + (lane << 1)); vals[0]=t.x; vals[1]=t.y; }
        else                 vals[0] = Trow[lane];
        float sq = vals[0]*vals[0] + vals[1]*vals[1] + vals[2]*vals[2] + vals[3]*vals[3];
#pragma unroll
        for (int i = 1; i < 64; i <<= 1) sq += __shfl_xor(sq, i, 64);
        const float wgt = rs[b0 + r] / (sqrtf(rq[b0 + r]) * sqrtf(sq));
        for (int j = 0; j < 4; ++j) accv[j] += vals[j] * wgt;
    }
    for (int j = 0; j < vecsz; ++j) sPart[wave * 256 + lane * vecsz + j] = accv[j];
    __syncthreads();
    if (tid < ysize)
        atomicAdd(&score[tid], sPart[tid] + sPart[256 + tid] + sPart[512 + tid] + sPart[768 + tid]);
    __syncthreads();
    if (tid == 0) {
        __threadfence();
        *lastFlag = (atomicAdd(counter, 1) == nHebb - 1) ? 1 : 0;
    }
    __syncthreads();
    if (!*lastFlag) return;
    float full = 0.f;
    if (tid < ysize) {
        float sc = atomicAdd(&score[tid], 0.f);
        full = (1.f - 1.f / (float)ysize) * rowsumH[tid] + sc;
    }
    sMin[tid] = (tid < ysize) ? full : 3.4e38f;
    sMax[tid] = (tid < ysize) ? full : -3.4e38f;
    __syncthreads();
    for (int st = 128; st > 0; st >>= 1) {
        if (tid < st) { sMin[tid] = fminf(sMin[tid], sMin[tid+st]); sMax[tid] = fmaxf(sMax[tid], sMax[tid+st]); }
        __syncthreads();
    }
    if (tid < ysize) {
        float nrm = (full - sMin[0]) / (sMax[0] - sMin[0] + 1e-8f);
        hm[tid] = (nrm < 0.5f) ? 0.f : 1.f;
    }
}

// ---------------------------------------------------------------------------
// epilogue (shared): C/D layout col=lane&15, row=q*4+reg  [m89-verified]
// ---------------------------------------------------------------------------
template<int MI, int NJ>
__device__ __forceinline__ void epilogue(
    floatx4 (&acc)[MI][NJ], int by, int bx, int TM, int TN,
    int wm, int wn, int q, int m16,
    const float* bias, const float* maskv,
    float* T, unsigned short* Xhl, float* outF,
    float* rs, float* rq, int Nh, int Nw, int NwReal)
{
    const int colW = bx * TN + wn * (TN / 2);
    const bool isHwave = (outF == nullptr) && (colW < Nh);
#pragma unroll
    for (int i = 0; i < MI; ++i) {
        const int row0 = by * TM + wm * (TM / 2) + i * 16 + q * 4;
        float rsum[4] = {0.f, 0.f, 0.f, 0.f}, rqsum[4] = {0.f, 0.f, 0.f, 0.f};
#pragma unroll
        for (int j = 0; j < NJ; ++j) {
            const int col = colW + j * 16 + m16;
            floatx4 vv = acc[i][j];
            if (outF) {
                if (col < NwReal) {
                    const float bb = bias[col];
#pragma unroll
                    for (int rg = 0; rg < 4; ++rg)
                        outF[(size_t)(row0 + rg) * NwReal + col] = fmaxf(vv[rg] + bb, 0.f);
                }
            } else if (isHwave) {
#pragma unroll
                for (int rg = 0; rg < 4; ++rg)
                    T[(size_t)(row0 + rg) * Nh + col] = vv[rg];
            } else {
                const int c = col - Nh;
                const float bb = bias[c], mm = maskv[c];
#pragma unroll
                for (int rg = 0; rg < 4; ++rg) {
                    const float xv = fmaxf(vv[rg] + bb, 0.f) * mm;
                    const unsigned short hi = f2bf(xv);
                    const unsigned short lo = f2bf(xv - bf2f(hi));
                    Xhl[(size_t)(row0 + rg) * (2 * Nw) + c] = hi;
                    Xhl[(size_t)(row0 + rg) * (2 * Nw) + Nw + c] = lo;
                    rsum[rg] += xv; rqsum[rg] += xv * xv;
                }
            }
        }
        if (rs && !isHwave && !outF) {
#pragma unroll
            for (int rg = 0; rg < 4; ++rg) {
                float a_ = rsum[rg], b_ = rqsum[rg];
#pragma unroll
                for (int d = 1; d < 16; d <<= 1) {
                    a_ += __shfl_xor(a_, d, 64);
                    b_ += __shfl_xor(b_, d, 64);
                }
                if (m16 == 0) {
                    atomicAdd(&rs[row0 + rg], a_);
                    atomicAdd(&rq[row0 + rg], b_);
                }
            }
        }
    }
}

// ---------------------------------------------------------------------------
// mfma_dbuf<TM,TN>: pipelined K-loop (32-k chunks, LDS double buffer).
// Blocks [0,nHebb) run hebb_dev on prev layer's T. GLD16 staging, XOR chunk
// swizzle (r>>1)&3 (2-way max, r7: 0 conflicts), XCD swizzle. 128 by-tiles.
// ---------------------------------------------------------------------------
template<int TM, int TN>
__global__ __launch_bounds__(256) void mfma_dbuf(
    const unsigned short* __restrict__ Ag, const unsigned short* __restrict__ Bg,
    const float* __restrict__ bias, const float* __restrict__ maskv,
    float* __restrict__ T, unsigned short* __restrict__ Xhl,
    float* __restrict__ outF,
    float* __restrict__ rs, float* __restrict__ rq,
    int K, int Nh, int Nw, int NwReal,
    const float* __restrict__ hT, const float* __restrict__ hrs,
    const float* __restrict__ hrq, const float* __restrict__ hrsH,
    float* __restrict__ hscore, int* __restrict__ hctr,
    float* __restrict__ hhm, int hy, int nHebb)
{
    constexpr int MI = TM / 32;
    constexpr int NJ = TN / 32;
    constexpr int IA = TM / 16;
    constexpr int IB = TN / 16;
    constexpr int NI = 2 * (IA + IB);
    constexpr int PERW = NI / 4;
    constexpr int BUFB = NI * 1024;
    __shared__ __align__(16) char lds[2 * BUFB];

    if ((int)blockIdx.x < nHebb) {
        hebb_dev(lds, blockIdx.x, hT, hrs, hrq, hrsH, hscore, hctr, hhm, hy, nHebb);
        return;
    }

    const int tid = threadIdx.x;
    const int w = tid >> 6, lane = tid & 63;
    const int q = lane >> 4, m16 = lane & 15;
    const int wm = w & 1, wn = w >> 1;

    const int lin = blockIdx.x - nHebb;
    const int g = lin & 7, idx = lin >> 3;
    const int by = g + 8 * (idx & 15);          // 128 by-tiles
    const int bx = idx >> 4;

    const int strideB = 4 * K;
    const int v = lane >> 2, u = lane & 3;

    const char* srcp[PERW];
#pragma unroll
    for (int t0 = 0; t0 < PERW; ++t0) {
        const int t = w * PERW + t0;
        int rloc; const char* base;
        if (t < IA)               { rloc = t * 16 + v;                 base = (const char*)Ag + (size_t)(by * TM + rloc) * strideB; }
        else if (t < 2 * IA)      { rloc = (t - IA) * 16 + v;          base = (const char*)Ag + (size_t)(by * TM + rloc) * strideB + 2 * K; }
        else if (t < 2 * IA + IB) { rloc = (t - 2 * IA) * 16 + v;      base = (const char*)Bg + (size_t)(bx * TN + rloc) * strideB; }
        else                      { rloc = (t - 2 * IA - IB) * 16 + v; base = (const char*)Bg + (size_t)(bx * TN + rloc) * strideB + 2 * K; }
        srcp[t0] = base + ((u ^ ((rloc >> 1) & 3)) << 4);
    }

    auto stage = [&](int buf, int k0) {
        char* dst = lds + buf * BUFB + (w * PERW) * 1024;
        const int kb = 2 * k0;
#pragma unroll
        for (int t0 = 0; t0 < PERW; ++t0)
            GLD16(srcp[t0] + kb, dst + t0 * 1024);
    };

    floatx4 acc[MI][NJ] = {};
    const int NIT = K / 32;

    stage(0, 0);
    int cur = 0;
    for (int it = 0; it < NIT; ++it) {
        __syncthreads();
        if (it + 1 < NIT) stage(cur ^ 1, (it + 1) * 32);
        const char* pb = lds + cur * BUFB;
        short8 ah[MI], al[MI], bh[NJ], bl[NJ];
#pragma unroll
        for (int i = 0; i < MI; ++i) {
            const int ra = wm * (TM / 2) + i * 16 + m16;
            const int so = ((q ^ ((ra >> 1) & 3)) << 4);
            ah[i] = *(const short8*)(pb + ra * 64 + so);
            al[i] = *(const short8*)(pb + IA * 1024 + ra * 64 + so);
        }
#pragma unroll
        for (int j = 0; j < NJ; ++j) {
            const int rb = wn * (TN / 2) + j * 16 + m16;
            const int so = ((q ^ ((rb >> 1) & 3)) << 4);
            bh[j] = *(const short8*)(pb + 2 * IA * 1024 + rb * 64 + so);
            bl[j] = *(const short8*)(pb + (2 * IA + IB) * 1024 + rb * 64 + so);
        }
#pragma unroll
        for (int i = 0; i < MI; ++i)
#pragma unroll
            for (int j = 0; j < NJ; ++j) {
                acc[i][j] = __builtin_amdgcn_mfma_f32_16x16x32_bf16(ah[i], bh[j], acc[i][j], 0, 0, 0);
                acc[i][j] = __builtin_amdgcn_mfma_f32_16x16x32_bf16(al[i], bh[j], acc[i][j], 0, 0, 0);
                acc[i][j] = __builtin_amdgcn_mfma_f32_16x16x32_bf16(ah[i], bl[j], acc[i][j], 0, 0, 0);
            }
        cur ^= 1;
    }

    epilogue<MI, NJ>(acc, by, bx, TM, TN, wm, wn, q, m16,
                     bias, maskv, T, Xhl, outF, rs, rq, Nh, Nw, NwReal);
}

// ---------------------------------------------------------------------------
// mfma_oneshot<TM,TN,KF>: small-K layers — stage the ENTIRE K extent into a
// single LDS buffer (4*(TM+TN)*KF bytes), ONE barrier, then MFMA straight
// through. Removes the degenerate 2-4-iteration pipeline entirely.
// Row bytes RB=2*KF (128|256): XOR swizzle r&7 -> 2-way max (free).
// ---------------------------------------------------------------------------
template<int TM, int TN, int KF>
__global__ __launch_bounds__(256) void mfma_oneshot(
    const unsigned short* __restrict__ Ag, const unsigned short* __restrict__ Bg,
    const float* __restrict__ bias, const float* __restrict__ maskv,
    float* __restrict__ T, unsigned short* __restrict__ Xhl,
    float* __restrict__ outF,
    float* __restrict__ rs, float* __restrict__ rq,
    int Nh, int Nw, int NwReal,
    const float* __restrict__ hT, const float* __restrict__ hrs,
    const float* __restrict__ hrq, const float* __restrict__ hrsH,
    float* __restrict__ hscore, int* __restrict__ hctr,
    float* __restrict__ hhm, int hy, int nHebb)
{
    static_assert(TM == TN, "section math assumes TM==TN");
    constexpr int MI = TM / 32;
    constexpr int NJ = TN / 32;
    constexpr int RB  = 2 * KF;          // bytes per section row
    constexpr int CPR = RB / 16;         // 16-B chunks per row (8|16)
    constexpr int RPI = 64 / CPR;        // rows per 1024-B instr
    constexpr int NIA = TM / RPI;        // instrs per section
    constexpr int NI  = 4 * NIA;
    constexpr int PERW = NI / 4;
    constexpr int SEC = TM * RB;         // bytes per section
    __shared__ __align__(16) char lds[NI * 1024];

    if ((int)blockIdx.x < nHebb) {
        hebb_dev(lds, blockIdx.x, hT, hrs, hrq, hrsH, hscore, hctr, hhm, hy, nHebb);
        return;
    }

    const int tid = threadIdx.x;
    const int w = tid >> 6, lane = tid & 63;
    const int q = lane >> 4, m16 = lane & 15;
    const int wm = w & 1, wn = w >> 1;

    const int lin = blockIdx.x - nHebb;
    const int g = lin & 7, idx = lin >> 3;
    const int by = g + 8 * (idx & 15);          // 128 by-tiles
    const int bx = idx >> 4;

    const int strideB = 4 * KF;
    const int v = lane / CPR, u = lane % CPR;

    // stage everything, one barrier
#pragma unroll
    for (int t0 = 0; t0 < PERW; ++t0) {
        const int t = w * PERW + t0;
        const int sec = t / NIA;
        const int rl = (t % NIA) * RPI + v;
        const char* base = (sec < 2)
            ? (const char*)Ag + (size_t)(by * TM + rl) * strideB + ((sec & 1) ? 2 * KF : 0)
            : (const char*)Bg + (size_t)(bx * TN + rl) * strideB + ((sec & 1) ? 2 * KF : 0);
        GLD16(base + ((u ^ (rl & 7)) << 4), lds + t * 1024);
    }
    __syncthreads();

    floatx4 acc[MI][NJ] = {};
#pragma unroll
    for (int h = 0; h < KF / 32; ++h) {
        short8 ah[MI], al[MI], bh[NJ], bl[NJ];
#pragma unroll
        for (int i = 0; i < MI; ++i) {
            const int ra = wm * (TM / 2) + i * 16 + m16;
            const int so = (((h * 4 + q) ^ (ra & 7)) << 4);
            ah[i] = *(const short8*)(lds + ra * RB + so);
            al[i] = *(const short8*)(lds + SEC + ra * RB + so);
        }
#pragma unroll
        for (int j = 0; j < NJ; ++j) {
            const int rb = wn * (TN / 2) + j * 16 + m16;
            const int so = (((h * 4 + q) ^ (rb & 7)) << 4);
            bh[j] = *(const short8*)(lds + 2 * SEC + rb * RB + so);
            bl[j] = *(const short8*)(lds + 3 * SEC + rb * RB + so);
        }
#pragma unroll
        for (int i = 0; i < MI; ++i)
#pragma unroll
            for (int j = 0; j < NJ; ++j) {
                acc[i][j] = __builtin_amdgcn_mfma_f32_16x16x32_bf16(ah[i], bh[j], acc[i][j], 0, 0, 0);
                acc[i][j] = __builtin_amdgcn_mfma_f32_16x16x32_bf16(al[i], bh[j], acc[i][j], 0, 0, 0);
                acc[i][j] = __builtin_amdgcn_mfma_f32_16x16x32_bf16(ah[i], bl[j], acc[i][j], 0, 0, 0);
            }
    }

    epilogue<MI, NJ>(acc, by, bx, TM, TN, wm, wn, q, m16,
                     bias, maskv, T, Xhl, outF, rs, rq, Nh, Nw, NwReal);
}

// ---------------------------------------------------------------------------
extern "C" void kernel_launch(void* const* d_in, const int* in_sizes, int n_in,
                              void* d_out, int out_size, void* d_ws, size_t ws_size,
                              hipStream_t stream)
{
    const float* x     = (const float*)d_in[0];
    const float* mask0 = (const float*)d_in[1];
    const float* mask1 = (const float*)d_in[2];
    const float* mask2 = (const float*)d_in[3];
    const float* W1 = (const float*)d_in[4];  const float* b1 = (const float*)d_in[5];
    const float* W2 = (const float*)d_in[6];  const float* b2 = (const float*)d_in[7];
    const float* W3 = (const float*)d_in[8];  const float* b3 = (const float*)d_in[9];
    const float* W4 = (const float*)d_in[10]; const float* b4 = (const float*)d_in[11];
    const float* H1 = (const float*)d_in[12];
    const float* H2 = (const float*)d_in[13];
    const float* H3 = (const float*)d_in[14];

    float* out = (float*)d_out;
    float* hm0 = out + (size_t)8192 * 1000;
    float* hm1 = hm0 + 256;
    float* hm2 = hm1 + 128;

    // ws layout (float units). Axhl (32 MB) dead after L1 -> X2hl/X3hl alias it.
    float* ws = (float*)d_ws;
    unsigned short* Axhl = (unsigned short*)ws;               // 8192*2048 bf16
    unsigned short* X2hl = (unsigned short*)ws;               // alias: 8192*512 shorts
    unsigned short* X3hl = (unsigned short*)(ws + 1048576);   // alias: 8192*256 shorts
    float* p = ws + 8388608;
    unsigned short* B1 = (unsigned short*)p;  p += 524288;    // 512*2048
    unsigned short* B2 = (unsigned short*)p;  p += 65536;     // 256*512
    unsigned short* B3 = (unsigned short*)p;  p += 16384;     // 128*256
    unsigned short* B4 = (unsigned short*)p;  p += 65536;     // 1024*128
    float* T1 = p; p += 2097152;                              // 8192*256 fp32
    float* T2 = p; p += 1048576;                              // 8192*128 fp32
    float* T3 = p; p += 524288;                               // 8192*64  fp32
    unsigned short* X1hl = (unsigned short*)p; p += 2097152;  // 8192*512 bf16 hl
    float* rs1 = p; p += 8192;  float* rq1 = p; p += 8192;
    float* rs2 = p; p += 8192;  float* rq2 = p; p += 8192;
    float* rs3 = p; p += 8192;  float* rq3 = p; p += 8192;
    float* rsH1 = p; p += 256;  float* rsH2 = p; p += 128;  float* rsH3 = p; p += 64;
    float* score1 = p; p += 256;
    float* score2 = p; p += 256;
    float* score3 = p; p += 256;
    int* ctr = (int*)p;

    convert_all<<<10112, 256, 0, stream>>>(
        x, Axhl, H1, W1, H2, W2, H3, W3, W4, B1, B2, B3, B4,
        rs1, rq1, rs2, rq2, rs3, rq3, rsH1, rsH2, rsH3,
        score1, score2, score3, ctr);

    // L1: T1 = x@H1^T, X1 = relu(x@W1^T+b1)*mask0 (+rs2/rq2).
    // 64x64 tiles -> 1024 gemm blocks = 4/CU (latency hiding via co-residency).
    mfma_dbuf<64, 64><<<1024, 256, 0, stream>>>(
        Axhl, B1, b1, mask0, T1, X1hl, nullptr, rs2, rq2,
        1024, 256, 256, 256,
        nullptr, nullptr, nullptr, nullptr, nullptr, nullptr, nullptr, 0, 0);

    // L2 (+hebb of layer1): 128 hebb + 512 gemm.
    mfma_dbuf<64, 64><<<640, 256, 0, stream>>>(
        X1hl, B2, b2, mask1, T2, X2hl, nullptr, rs3, rq3,
        256, 128, 128, 128,
        T1, rs1, rq1, rsH1, score1, ctr + 0, hm0, 256, 128);

    // L3 (+hebb of layer2): one-shot K=128 (64 KB LDS). 128 hebb + 256 gemm.
    mfma_oneshot<64, 64, 128><<<384, 256, 0, stream>>>(
        X2hl, B3, b3, mask2, T3, X3hl, nullptr, nullptr, nullptr,
        64, 64, 64,
        T2, rs2, rq2, rsH2, score2, ctr + 1, hm1, 128, 128);

    // L4 (+hebb of layer3): one-shot K=64 (32 KB LDS), out=relu(X3@W4^T+b4),
    // N=1000 (B padded 1024). 128 hebb + 2048 gemm = 8/CU.
    mfma_oneshot<64, 64, 64><<<2176, 256, 0, stream>>>(
        X3hl, B4, b4, nullptr, nullptr, nullptr, out, nullptr, nullptr,
        0, 1024, 1000,
        T3, rs3, rq3, rsH3, score3, ctr + 2, hm2, 64, 128);
}